// Round 1
// baseline (1207.202 us; speedup 1.0000x reference)
//
#include <hip/hip_runtime.h>
#include <cstdint>
#include <cstddef>

#define N_NODES 50000
#define N_EDGES 400000
#define D_IN 512
#define D_OUT 512
#define D_H 1024            // [W | W_res] packed
#define M_PAD 50048         // 391 * 128
#define NEG_SLOPE 0.01f
#define FILL 2.0f

typedef __bf16 bf16x8 __attribute__((ext_vector_type(8)));
typedef float f32x4 __attribute__((ext_vector_type(4)));

__device__ inline unsigned short f2bf(float f) {
    unsigned int u = __float_as_uint(f);
    unsigned int r = (u + 0x7FFFu + ((u >> 16) & 1u)) >> 16;
    return (unsigned short)r;
}
__device__ inline float bf2f(unsigned short b) {
    return __uint_as_float(((unsigned int)b) << 16);
}

// ---------------- norm / CSR construction ----------------

__global__ void init_kernel(float* deg, int* counts, int* cursor) {
    int i = blockIdx.x * blockDim.x + threadIdx.x;
    if (i < N_NODES) { deg[i] = FILL; counts[i] = 0; cursor[i] = 0; }
}

__global__ void edge_deg_kernel(const int* __restrict__ adj, const float* __restrict__ w,
                                float* deg, int* counts) {
    int e = blockIdx.x * blockDim.x + threadIdx.x;
    if (e < N_EDGES) {
        int d = adj[N_EDGES + e];
        atomicAdd(&deg[d], w[e]);
        atomicAdd(&counts[d], 1);
    }
}

__global__ void dis_kernel(const float* __restrict__ deg, float* __restrict__ dis) {
    int i = blockIdx.x * blockDim.x + threadIdx.x;
    if (i < N_NODES) {
        float g = deg[i];
        dis[i] = (g > 0.0f) ? rsqrtf(g) : 0.0f;
    }
}

// single-block exclusive scan of counts[N] -> offsets[N+1]
__global__ void scan_kernel(const int* __restrict__ counts, int* __restrict__ offsets) {
    __shared__ int wsum[4];
    __shared__ int carry_s;
    int tid = threadIdx.x;
    int lane = tid & 63, wid = tid >> 6;
    if (tid == 0) carry_s = 0;
    __syncthreads();
    for (int base = 0; base < N_NODES; base += 256) {
        int i = base + tid;
        int orig = (i < N_NODES) ? counts[i] : 0;
        int v = orig;
        #pragma unroll
        for (int d = 1; d < 64; d <<= 1) {
            int t = __shfl_up(v, d, 64);
            if (lane >= d) v += t;
        }
        if (lane == 63) wsum[wid] = v;
        __syncthreads();
        int s = 0;
        for (int ww = 0; ww < wid; ++ww) s += wsum[ww];
        int excl = carry_s + s + v - orig;
        if (i < N_NODES) offsets[i] = excl;
        int total = wsum[0] + wsum[1] + wsum[2] + wsum[3];
        __syncthreads();
        if (tid == 0) carry_s += total;
        __syncthreads();
    }
    if (tid == 0) offsets[N_NODES] = carry_s;
}

__global__ void fill_kernel(const int* __restrict__ adj, const float* __restrict__ w,
                            const float* __restrict__ dis, const int* __restrict__ offsets,
                            int* cursor, int* __restrict__ csr_src, float* __restrict__ csr_val) {
    int e = blockIdx.x * blockDim.x + threadIdx.x;
    if (e < N_EDGES) {
        int s = adj[e];
        int d = adj[N_EDGES + e];
        float v = dis[s] * w[e] * dis[d];
        int pos = offsets[d] + atomicAdd(&cursor[d], 1);
        csr_src[pos] = s;
        csr_val[pos] = v;
    }
}

// ---------------- conversions ----------------

// Wct[n][k] = (n<512 ? W[k][n] : W_res[k][n-512]) as bf16, row-major [1024][512]
__global__ void convert_w_kernel(const float* __restrict__ W, const float* __restrict__ Wres,
                                 unsigned short* __restrict__ Wct) {
    int idx = blockIdx.x * blockDim.x + threadIdx.x;
    if (idx < D_H * D_IN) {
        int n = idx >> 9, k = idx & 511;
        float v = (n < D_OUT) ? W[k * D_OUT + n] : Wres[k * D_OUT + (n - D_OUT)];
        Wct[idx] = f2bf(v);
    }
}

// x fp32 [50000][512] -> Xb bf16 [50048][512], pad rows zero
__global__ void convert_x_kernel(const float* __restrict__ x, unsigned short* __restrict__ Xb) {
    int gid = blockIdx.x * blockDim.x + threadIdx.x;
    long base = (long)gid * 4;
    if (base >= (long)M_PAD * D_IN) return;
    int row = (int)(base >> 9);
    ushort4 o;
    if (row < N_NODES) {
        const float4 v = *reinterpret_cast<const float4*>(x + base);
        o.x = f2bf(v.x); o.y = f2bf(v.y); o.z = f2bf(v.z); o.w = f2bf(v.w);
    } else {
        o.x = 0; o.y = 0; o.z = 0; o.w = 0;
    }
    *reinterpret_cast<ushort4*>(Xb + base) = o;
}

// ---------------- GEMM: H[M_PAD][1024] = Xb[M_PAD][512] * Wct^T ----------------
// (Wct is [n][k], so C[m][n] = sum_k A[m][k]*Wct[n][k])

__device__ inline void gload_lds16(const void* g, void* l) {
    __builtin_amdgcn_global_load_lds(
        (const __attribute__((address_space(1))) void*)g,
        (__attribute__((address_space(3))) void*)l, 16, 0, 0);
}

__global__ __launch_bounds__(256)
void gemm_kernel(const unsigned short* __restrict__ Xb, const unsigned short* __restrict__ Wct,
                 unsigned short* __restrict__ H) {
    __shared__ __align__(16) __bf16 Asm[128 * 32];
    __shared__ __align__(16) __bf16 Bsm[128 * 32];
    int tid = threadIdx.x;
    int lane = tid & 63, wid = tid >> 6;
    int wm = wid & 1, wn = wid >> 1;
    int rowBase = blockIdx.x * 128;
    int colBase = blockIdx.y * 128;

    f32x4 acc[4][4];
    #pragma unroll
    for (int i = 0; i < 4; ++i)
        #pragma unroll
        for (int j = 0; j < 4; ++j)
            acc[i][j] = (f32x4){0.f, 0.f, 0.f, 0.f};

    const unsigned short* Ag = Xb + (size_t)rowBase * D_IN;
    const unsigned short* Bg = Wct + (size_t)colBase * D_IN;

    for (int k0 = 0; k0 < D_IN; k0 += 32) {
        __syncthreads();
        #pragma unroll
        for (int t = 0; t < 2; ++t) {
            int idx = t * 256 + tid;
            int row = idx >> 2, ch = idx & 3;
            gload_lds16(Ag + (size_t)row * D_IN + k0 + ch * 8, (char*)Asm + idx * 16);
            gload_lds16(Bg + (size_t)row * D_IN + k0 + ch * 8, (char*)Bsm + idx * 16);
        }
        __syncthreads();
        bf16x8 aF[4], bF[4];
        #pragma unroll
        for (int i = 0; i < 4; ++i)
            aF[i] = *reinterpret_cast<const bf16x8*>(&Asm[(wm * 64 + i * 16 + (lane & 15)) * 32 + (lane >> 4) * 8]);
        #pragma unroll
        for (int j = 0; j < 4; ++j)
            bF[j] = *reinterpret_cast<const bf16x8*>(&Bsm[(wn * 64 + j * 16 + (lane & 15)) * 32 + (lane >> 4) * 8]);
        #pragma unroll
        for (int i = 0; i < 4; ++i)
            #pragma unroll
            for (int j = 0; j < 4; ++j)
                acc[i][j] = __builtin_amdgcn_mfma_f32_16x16x32_bf16(aF[i], bF[j], acc[i][j], 0, 0, 0);
    }

    int q = lane >> 4, c = lane & 15;
    #pragma unroll
    for (int i = 0; i < 4; ++i)
        #pragma unroll
        for (int j = 0; j < 4; ++j)
            #pragma unroll
            for (int r = 0; r < 4; ++r) {
                int row = rowBase + wm * 64 + i * 16 + q * 4 + r;
                int col = colBase + wn * 64 + j * 16 + c;
                H[(size_t)row * D_H + col] = f2bf(acc[i][j][r]);
            }
}

// ---------------- gather + residual + leaky_relu ----------------
// out[node][c..c+3] = leaky( H[node][512+c..] + selfw*H[node][c..] + sum_e val_e * H[src_e][c..] )

__global__ __launch_bounds__(128)
void gather_kernel(const unsigned short* __restrict__ H, const int* __restrict__ offsets,
                   const int* __restrict__ csr_src, const float* __restrict__ csr_val,
                   const float* __restrict__ dis, float* __restrict__ out) {
    int node = blockIdx.x;
    int c = threadIdx.x * 4;
    const unsigned short* hrow = H + (size_t)node * D_H;
    float dn = dis[node];
    float selfw = FILL * dn * dn;
    ushort4 hs = *reinterpret_cast<const ushort4*>(hrow + c);
    ushort4 rr = *reinterpret_cast<const ushort4*>(hrow + D_OUT + c);
    float a0 = bf2f(rr.x) + selfw * bf2f(hs.x);
    float a1 = bf2f(rr.y) + selfw * bf2f(hs.y);
    float a2 = bf2f(rr.z) + selfw * bf2f(hs.z);
    float a3 = bf2f(rr.w) + selfw * bf2f(hs.w);
    int beg = offsets[node], end = offsets[node + 1];
    for (int e = beg; e < end; ++e) {
        int s = csr_src[e];
        float v = csr_val[e];
        ushort4 hb = *reinterpret_cast<const ushort4*>(H + (size_t)s * D_H + c);
        a0 += v * bf2f(hb.x);
        a1 += v * bf2f(hb.y);
        a2 += v * bf2f(hb.z);
        a3 += v * bf2f(hb.w);
    }
    float4 o;
    o.x = (a0 >= 0.0f) ? a0 : NEG_SLOPE * a0;
    o.y = (a1 >= 0.0f) ? a1 : NEG_SLOPE * a1;
    o.z = (a2 >= 0.0f) ? a2 : NEG_SLOPE * a2;
    o.w = (a3 >= 0.0f) ? a3 : NEG_SLOPE * a3;
    *reinterpret_cast<float4*>(out + (size_t)node * D_OUT + c) = o;
}

// ---------------- launch ----------------

extern "C" void kernel_launch(void* const* d_in, const int* in_sizes, int n_in,
                              void* d_out, int out_size, void* d_ws, size_t ws_size,
                              hipStream_t stream) {
    const float* x[3] = { (const float*)d_in[0], (const float*)d_in[1], (const float*)d_in[2] };
    const int* adj = (const int*)d_in[3];
    const float* aw = (const float*)d_in[4];
    const float* W = (const float*)d_in[5];
    const float* Wres = (const float*)d_in[6];
    float* out = (float*)d_out;

    char* base = (char*)d_ws;
    size_t off = 0;
    auto carve = [&](size_t bytes) -> void* {
        void* p = base + off;
        off += (bytes + 255) & ~(size_t)255;
        return p;
    };
    float* deg       = (float*)carve(sizeof(float) * N_NODES);
    float* dis       = (float*)carve(sizeof(float) * N_NODES);
    int*   counts    = (int*)carve(sizeof(int) * N_NODES);
    int*   offsets   = (int*)carve(sizeof(int) * (N_NODES + 1));
    int*   cursor    = (int*)carve(sizeof(int) * N_NODES);
    int*   csr_src   = (int*)carve(sizeof(int) * N_EDGES);
    float* csr_val   = (float*)carve(sizeof(float) * N_EDGES);
    unsigned short* Wct = (unsigned short*)carve(sizeof(unsigned short) * D_H * D_IN);
    unsigned short* Xb  = (unsigned short*)carve(sizeof(unsigned short) * (size_t)M_PAD * D_IN);
    unsigned short* H   = (unsigned short*)carve(sizeof(unsigned short) * (size_t)M_PAD * D_H);

    // norm + CSR
    init_kernel<<<(N_NODES + 255) / 256, 256, 0, stream>>>(deg, counts, cursor);
    edge_deg_kernel<<<(N_EDGES + 255) / 256, 256, 0, stream>>>(adj, aw, deg, counts);
    dis_kernel<<<(N_NODES + 255) / 256, 256, 0, stream>>>(deg, dis);
    scan_kernel<<<1, 256, 0, stream>>>(counts, offsets);
    fill_kernel<<<(N_EDGES + 255) / 256, 256, 0, stream>>>(adj, aw, dis, offsets, cursor, csr_src, csr_val);

    // weights
    convert_w_kernel<<<(D_H * D_IN + 255) / 256, 256, 0, stream>>>(W, Wres, Wct);

    // per-conv pipeline (reuse Xb / H buffers)
    const int xconv_blocks = (int)(((size_t)M_PAD * D_IN / 4 + 255) / 256);
    dim3 gemm_grid(M_PAD / 128, D_H / 128);
    for (int cidx = 0; cidx < 3; ++cidx) {
        convert_x_kernel<<<xconv_blocks, 256, 0, stream>>>(x[cidx], Xb);
        gemm_kernel<<<gemm_grid, 256, 0, stream>>>(Xb, Wct, H);
        gather_kernel<<<N_NODES, 128, 0, stream>>>(H, offsets, csr_src, csr_val, dis,
                                                   out + (size_t)cidx * N_NODES * D_OUT);
    }
}

// Round 2
// 1089.635 us; speedup vs baseline: 1.1079x; 1.1079x over previous
//
#include <hip/hip_runtime.h>
#include <cstdint>
#include <cstddef>

#define N_NODES 50000
#define N_EDGES 400000
#define D_IN 512
#define D_OUT 512
#define D_K 1024            // packed K: [Xagg | Xb]
#define M_PAD 50048         // 391 * 128
#define MBLKS 391           // M_PAD / 128
#define NEG_SLOPE 0.01f
#define FILL 2.0f
#define SCAN_NBLK 196       // ceil(50000/256)

typedef __bf16 bf16x8 __attribute__((ext_vector_type(8)));
typedef float f32x4 __attribute__((ext_vector_type(4)));
typedef unsigned short ushort8v __attribute__((ext_vector_type(8)));

__device__ inline unsigned short f2bf(float f) {
    unsigned int u = __float_as_uint(f);
    unsigned int r = (u + 0x7FFFu + ((u >> 16) & 1u)) >> 16;
    return (unsigned short)r;
}
__device__ inline float bf2f(unsigned short b) {
    return __uint_as_float(((unsigned int)b) << 16);
}

// ---------------- norm / CSR construction ----------------

__global__ void init_kernel(float* deg, int* counts, int* cursor) {
    int i = blockIdx.x * blockDim.x + threadIdx.x;
    if (i < N_NODES) { deg[i] = FILL; counts[i] = 0; cursor[i] = 0; }
}

__global__ void edge_deg_kernel(const int* __restrict__ adj, const float* __restrict__ w,
                                float* deg, int* counts) {
    int e = blockIdx.x * blockDim.x + threadIdx.x;
    if (e < N_EDGES) {
        int d = adj[N_EDGES + e];
        atomicAdd(&deg[d], w[e]);
        atomicAdd(&counts[d], 1);
    }
}

__global__ void dis_kernel(const float* __restrict__ deg, float* __restrict__ dis) {
    int i = blockIdx.x * blockDim.x + threadIdx.x;
    if (i < N_NODES) {
        float g = deg[i];
        dis[i] = (g > 0.0f) ? rsqrtf(g) : 0.0f;
    }
}

// hierarchical exclusive scan of counts[N] -> offsets[N+1]
// scan1: per-block local exclusive scan into offsets, block totals into bsum
__global__ __launch_bounds__(256)
void scan1_kernel(const int* __restrict__ counts, int* __restrict__ offsets,
                  int* __restrict__ bsum) {
    __shared__ int wsum[4];
    int tid = threadIdx.x;
    int lane = tid & 63, wid = tid >> 6;
    int i = blockIdx.x * 256 + tid;
    int orig = (i < N_NODES) ? counts[i] : 0;
    int v = orig;
    #pragma unroll
    for (int d = 1; d < 64; d <<= 1) {
        int t = __shfl_up(v, d, 64);
        if (lane >= d) v += t;
    }
    if (lane == 63) wsum[wid] = v;
    __syncthreads();
    int add = 0;
    for (int ww = 0; ww < wid; ++ww) add += wsum[ww];
    int incl = v + add;
    if (i < N_NODES) offsets[i] = incl - orig;
    if (tid == 255) bsum[blockIdx.x] = incl;
}

// scan2: single block scans bsum[SCAN_NBLK] -> exclusive bscan, total at bscan[SCAN_NBLK]
__global__ __launch_bounds__(256)
void scan2_kernel(const int* __restrict__ bsum, int* __restrict__ bscan) {
    __shared__ int wsum[4];
    int tid = threadIdx.x;
    int lane = tid & 63, wid = tid >> 6;
    int orig = (tid < SCAN_NBLK) ? bsum[tid] : 0;
    int v = orig;
    #pragma unroll
    for (int d = 1; d < 64; d <<= 1) {
        int t = __shfl_up(v, d, 64);
        if (lane >= d) v += t;
    }
    if (lane == 63) wsum[wid] = v;
    __syncthreads();
    int add = 0;
    for (int ww = 0; ww < wid; ++ww) add += wsum[ww];
    int incl = v + add;
    if (tid < SCAN_NBLK) bscan[tid] = incl - orig;
    if (tid == 255) bscan[SCAN_NBLK] = incl;
}

// scan3: offsets[i] += bscan[block]; offsets[N] = total
__global__ __launch_bounds__(256)
void scan3_kernel(int* __restrict__ offsets, const int* __restrict__ bscan) {
    int i = blockIdx.x * 256 + threadIdx.x;
    if (i < N_NODES) offsets[i] += bscan[blockIdx.x];
    if (i == N_NODES) offsets[N_NODES] = bscan[SCAN_NBLK];
}

__global__ void fill_kernel(const int* __restrict__ adj, const float* __restrict__ w,
                            const float* __restrict__ dis, const int* __restrict__ offsets,
                            int* cursor, int* __restrict__ csr_src, float* __restrict__ csr_val) {
    int e = blockIdx.x * blockDim.x + threadIdx.x;
    if (e < N_EDGES) {
        int s = adj[e];
        int d = adj[N_EDGES + e];
        float v = dis[s] * w[e] * dis[d];
        int pos = offsets[d] + atomicAdd(&cursor[d], 1);
        csr_src[pos] = s;
        csr_val[pos] = v;
    }
}

// ---------------- conversions ----------------

// Wcb[n][k] = (k<512 ? W[k][n] : W_res[k-512][n]) as bf16, row-major [512][1024]
__global__ void convert_w_kernel(const float* __restrict__ W, const float* __restrict__ Wres,
                                 unsigned short* __restrict__ Wcb) {
    int idx = blockIdx.x * blockDim.x + threadIdx.x;
    if (idx < D_OUT * D_K) {
        int n = idx >> 10, k = idx & 1023;
        float v = (k < D_IN) ? W[(size_t)k * D_OUT + n] : Wres[(size_t)(k - D_IN) * D_OUT + n];
        Wcb[idx] = f2bf(v);
    }
}

// x fp32 [3][50000][512] -> Xcat bf16 [3][50048][1024] (Xb half at cols 512..1023);
// pad rows zeroed in both halves.
__global__ void convert_x_kernel(const float* __restrict__ x0, const float* __restrict__ x1,
                                 const float* __restrict__ x2, unsigned short* __restrict__ Xcat) {
    size_t gid = (size_t)blockIdx.x * blockDim.x + threadIdx.x;
    size_t base = gid * 8;
    if (base >= (size_t)3 * M_PAD * D_IN) return;
    int conv = (int)(base / ((size_t)M_PAD * D_IN));
    size_t rem = base - (size_t)conv * M_PAD * D_IN;
    int row = (int)(rem >> 9);
    int col = (int)(rem & 511);
    unsigned short* dst = Xcat + ((size_t)conv * M_PAD + row) * D_K;
    ushort8v o;
    if (row < N_NODES) {
        const float* xs = (conv == 0 ? x0 : (conv == 1 ? x1 : x2));
        const float4 v0 = *reinterpret_cast<const float4*>(xs + (size_t)row * D_IN + col);
        const float4 v1 = *reinterpret_cast<const float4*>(xs + (size_t)row * D_IN + col + 4);
        o[0] = f2bf(v0.x); o[1] = f2bf(v0.y); o[2] = f2bf(v0.z); o[3] = f2bf(v0.w);
        o[4] = f2bf(v1.x); o[5] = f2bf(v1.y); o[6] = f2bf(v1.z); o[7] = f2bf(v1.w);
    } else {
        #pragma unroll
        for (int j = 0; j < 8; ++j) o[j] = 0;
        *reinterpret_cast<ushort8v*>(dst + col) = o;     // zero Xagg half of pad row
    }
    *reinterpret_cast<ushort8v*>(dst + D_IN + col) = o;  // Xb half
}

// ---------------- gather: Xagg = A_norm @ Xb (incl. self loop) ----------------
// One wave per node; lane reads 8 bf16 (16 B). Xcat is this conv's base.

__global__ __launch_bounds__(256)
void gather_kernel(unsigned short* __restrict__ Xcat, const int* __restrict__ offsets,
                   const int* __restrict__ csr_src, const float* __restrict__ csr_val,
                   const float* __restrict__ dis) {
    int wid = threadIdx.x >> 6;
    int lane = threadIdx.x & 63;
    int node = blockIdx.x * 4 + wid;
    if (node >= N_NODES) return;
    const unsigned short* xb = Xcat + D_IN + (size_t)lane * 8;
    float dn = dis[node];
    float selfw = FILL * dn * dn;
    ushort8v hs = *reinterpret_cast<const ushort8v*>(xb + (size_t)node * D_K);
    float a[8];
    #pragma unroll
    for (int j = 0; j < 8; ++j) a[j] = selfw * bf2f(hs[j]);
    int beg = offsets[node], end = offsets[node + 1];
    int e = beg;
    for (; e + 1 < end; e += 2) {
        int s0 = csr_src[e], s1 = csr_src[e + 1];
        float v0 = csr_val[e], v1 = csr_val[e + 1];
        ushort8v h0 = *reinterpret_cast<const ushort8v*>(xb + (size_t)s0 * D_K);
        ushort8v h1 = *reinterpret_cast<const ushort8v*>(xb + (size_t)s1 * D_K);
        #pragma unroll
        for (int j = 0; j < 8; ++j) a[j] += v0 * bf2f(h0[j]);
        #pragma unroll
        for (int j = 0; j < 8; ++j) a[j] += v1 * bf2f(h1[j]);
    }
    if (e < end) {
        int s0 = csr_src[e];
        float v0 = csr_val[e];
        ushort8v h0 = *reinterpret_cast<const ushort8v*>(xb + (size_t)s0 * D_K);
        #pragma unroll
        for (int j = 0; j < 8; ++j) a[j] += v0 * bf2f(h0[j]);
    }
    ushort8v o;
    #pragma unroll
    for (int j = 0; j < 8; ++j) o[j] = f2bf(a[j]);
    *reinterpret_cast<ushort8v*>(Xcat + (size_t)node * D_K + lane * 8) = o;
}

// ---------------- GEMM: out = leaky(Xcat[3*M_PAD][1024] @ Wcb^T) ----------------

__device__ inline void gload_lds16(const void* g, void* l) {
    __builtin_amdgcn_global_load_lds(
        (const __attribute__((address_space(1))) void*)g,
        (__attribute__((address_space(3))) void*)l, 16, 0, 0);
}

__global__ __launch_bounds__(256)
void gemm_kernel(const unsigned short* __restrict__ Xcat, const unsigned short* __restrict__ Wcb,
                 float* __restrict__ out) {
    __shared__ __align__(16) __bf16 Asm[128 * 32];
    __shared__ __align__(16) __bf16 Bsm[128 * 32];
    int tid = threadIdx.x;
    int lane = tid & 63, wid = tid >> 6;
    int wm = wid & 1, wn = wid >> 1;
    int mblk = blockIdx.x;
    int conv = mblk / MBLKS;
    int rowBase = mblk * 128;
    int nodeBase = rowBase - conv * M_PAD;
    int colBase = blockIdx.y * 128;

    f32x4 acc[4][4];
    #pragma unroll
    for (int i = 0; i < 4; ++i)
        #pragma unroll
        for (int j = 0; j < 4; ++j)
            acc[i][j] = (f32x4){0.f, 0.f, 0.f, 0.f};

    const unsigned short* Ag = Xcat + (size_t)rowBase * D_K;
    const unsigned short* Bg = Wcb + (size_t)colBase * D_K;

    for (int k0 = 0; k0 < D_K; k0 += 32) {
        __syncthreads();
        #pragma unroll
        for (int t = 0; t < 2; ++t) {
            int idx = t * 256 + tid;
            int row = idx >> 2, ch = idx & 3;
            gload_lds16(Ag + (size_t)row * D_K + k0 + ch * 8, (char*)Asm + idx * 16);
            gload_lds16(Bg + (size_t)row * D_K + k0 + ch * 8, (char*)Bsm + idx * 16);
        }
        __syncthreads();
        bf16x8 aF[4], bF[4];
        #pragma unroll
        for (int i = 0; i < 4; ++i)
            aF[i] = *reinterpret_cast<const bf16x8*>(&Asm[(wm * 64 + i * 16 + (lane & 15)) * 32 + (lane >> 4) * 8]);
        #pragma unroll
        for (int j = 0; j < 4; ++j)
            bF[j] = *reinterpret_cast<const bf16x8*>(&Bsm[(wn * 64 + j * 16 + (lane & 15)) * 32 + (lane >> 4) * 8]);
        #pragma unroll
        for (int i = 0; i < 4; ++i)
            #pragma unroll
            for (int j = 0; j < 4; ++j)
                acc[i][j] = __builtin_amdgcn_mfma_f32_16x16x32_bf16(aF[i], bF[j], acc[i][j], 0, 0, 0);
    }

    int q = lane >> 4, c = lane & 15;
    float* obase = out + (size_t)conv * N_NODES * D_OUT;
    #pragma unroll
    for (int i = 0; i < 4; ++i)
        #pragma unroll
        for (int j = 0; j < 4; ++j)
            #pragma unroll
            for (int r = 0; r < 4; ++r) {
                int node = nodeBase + wm * 64 + i * 16 + q * 4 + r;
                int col = colBase + wn * 64 + j * 16 + c;
                if (node < N_NODES) {
                    float v = acc[i][j][r];
                    v = (v >= 0.0f) ? v : NEG_SLOPE * v;
                    __builtin_nontemporal_store(v, obase + (size_t)node * D_OUT + col);
                }
            }
}

// ---------------- launch ----------------

extern "C" void kernel_launch(void* const* d_in, const int* in_sizes, int n_in,
                              void* d_out, int out_size, void* d_ws, size_t ws_size,
                              hipStream_t stream) {
    const float* x0 = (const float*)d_in[0];
    const float* x1 = (const float*)d_in[1];
    const float* x2 = (const float*)d_in[2];
    const int* adj = (const int*)d_in[3];
    const float* aw = (const float*)d_in[4];
    const float* W = (const float*)d_in[5];
    const float* Wres = (const float*)d_in[6];
    float* out = (float*)d_out;

    char* base = (char*)d_ws;
    size_t off = 0;
    auto carve = [&](size_t bytes) -> void* {
        void* p = base + off;
        off += (bytes + 255) & ~(size_t)255;
        return p;
    };
    float* deg     = (float*)carve(sizeof(float) * N_NODES);
    float* dis     = (float*)carve(sizeof(float) * N_NODES);
    int*   counts  = (int*)carve(sizeof(int) * N_NODES);
    int*   offsets = (int*)carve(sizeof(int) * (N_NODES + 1));
    int*   cursor  = (int*)carve(sizeof(int) * N_NODES);
    int*   bsum    = (int*)carve(sizeof(int) * SCAN_NBLK);
    int*   bscan   = (int*)carve(sizeof(int) * (SCAN_NBLK + 1));
    int*   csr_src = (int*)carve(sizeof(int) * N_EDGES);
    float* csr_val = (float*)carve(sizeof(float) * N_EDGES);
    unsigned short* Wcb  = (unsigned short*)carve(sizeof(unsigned short) * D_OUT * D_K);
    unsigned short* Xcat = (unsigned short*)carve(sizeof(unsigned short) * (size_t)3 * M_PAD * D_K);

    // norm + CSR
    init_kernel<<<(N_NODES + 255) / 256, 256, 0, stream>>>(deg, counts, cursor);
    edge_deg_kernel<<<(N_EDGES + 255) / 256, 256, 0, stream>>>(adj, aw, deg, counts);
    dis_kernel<<<(N_NODES + 255) / 256, 256, 0, stream>>>(deg, dis);
    scan1_kernel<<<SCAN_NBLK, 256, 0, stream>>>(counts, offsets, bsum);
    scan2_kernel<<<1, 256, 0, stream>>>(bsum, bscan);
    scan3_kernel<<<SCAN_NBLK, 256, 0, stream>>>(offsets, bscan);
    fill_kernel<<<(N_EDGES + 255) / 256, 256, 0, stream>>>(adj, aw, dis, offsets, cursor, csr_src, csr_val);

    // weight pack + x convert (all 3)
    convert_w_kernel<<<(D_OUT * D_K + 255) / 256, 256, 0, stream>>>(W, Wres, Wcb);
    {
        size_t total = (size_t)3 * M_PAD * D_IN / 8;
        convert_x_kernel<<<(unsigned)((total + 255) / 256), 256, 0, stream>>>(x0, x1, x2, Xcat);
    }

    // gathers (aggregate-first), one per conv to keep working set in LLC
    for (int cidx = 0; cidx < 3; ++cidx)
        gather_kernel<<<N_NODES / 4, 256, 0, stream>>>(Xcat + (size_t)cidx * M_PAD * D_K,
                                                       offsets, csr_src, csr_val, dis);

    // one batched GEMM with fused leaky-relu epilogue
    dim3 gemm_grid(3 * MBLKS, D_K / 256);
    gemm_grid.y = 4;  // N=512 -> 4 col-blocks of 128
    gemm_kernel<<<gemm_grid, 256, 0, stream>>>(Xcat, Wcb, out);
}